// Round 6
// baseline (52.385 us; speedup 1.0000x reference)
//
#include <hip/hip_runtime.h>

// Shapes fixed by setup_inputs(): b=8, t=128, k=128, h=4, m=t-1=127.
#define KD 128
#define NH 4
#define MM 127
#define NPRE 516    // Wct precompute blocks (one per Wv row)

// workspace layout (float offsets)
#define OFF_WC 0            // [4][256][128]  Wct[h][c][dd]  (c-major)
#define OFF_C  131072       // [1024][512]    weighted kv sums per (bt, h*128+d)

typedef const __attribute__((address_space(1))) void* gas_t;
typedef __attribute__((address_space(3))) void* las_t;

// ---------------------------------------------------------------------------
// Kernel 1 (block-specialized):
//  blocks 0..515    : Wct[h][c][dd] = W1|W2 value rows (c-major for proj)
//  blocks 516..1539 : per-(b,t) attention c-sum.
//    Staging uses global_load_lds DMA (no reg result -> 16 loads/thread in
//    flight structurally; rounds 2-5 were latency-bound because the compiler
//    serialized register-dependent loads: 894 GB/s, 40us).
// (q/W2/bias score terms are constant in m -> cancel in softmax -> dropped.)
// ---------------------------------------------------------------------------
__global__ __launch_bounds__(256, 2)
void attn_fused(const float* __restrict__ kv_x,
                const float* __restrict__ Wk,
                const float* __restrict__ Wq,
                const float* __restrict__ Wv,
                float* __restrict__ ws) {
    const int bid = blockIdx.x;
    const int tid = threadIdx.x;

    if (bid < NPRE) {
        // ---- Wct precompute ----
        int o = bid;
        int h = o / 129, r = o - h * 129;
        if (r == 0) return;              // score rows: computed per attn WG
        int dd = r - 1;
        int which = tid >> 7, k = tid & 127;
        const float* W = which ? Wq : Wk;
        const float* wvrow = Wv + (size_t)o * 256 + which * 128;
        float acc = 0.f;
        #pragma unroll 8
        for (int j = 0; j < 128; ++j)
            acc += wvrow[j] * W[j * 128 + k];
        ws[OFF_WC + (size_t)(h * 256 + which * 128 + k) * 128 + dd] = acc;
        return;
    }

    // ---------------- attention path ----------------
    __shared__ float skv[128 * KD];    // kv tile, row 127 = junk pad (65536 B)
    __shared__ float sW1s[NH * KD];    // score rows           (2 KB)
    __shared__ float ssc[512];         // scores [m][h]        (2 KB)
    __shared__ float swt[512];         // weights [m][h]       (2 KB)
    __shared__ float cpart[4][512];    // row-group partials   (8 KB)
    // total 79872 B -> 2 WG/CU

    const int bt = bid - NPRE;
    const int dq = tid & 31;           // d-quad (d = dq*4+j)
    const int g  = tid >> 5;           // 32-lane group 0..7
    const int wv_ = tid >> 6;          // wave 0..3

    // ---- per-WG W1S first (its VMEM loads issue before the DMA stream,
    //      so their waits don't drain the DMA queue) ----
    {
        int h0 = tid >> 7;             // 0/1; also h0+2
        int k  = tid & 127;
        const float* r0 = Wv + (size_t)(129 * h0) * 256;
        const float* r2 = Wv + (size_t)(129 * (h0 + 2)) * 256;
        float a0 = 0.f, a1 = 0.f;
        #pragma unroll 8
        for (int j = 0; j < 128; ++j) {
            float wk = Wk[j * 128 + k];
            a0 += r0[j] * wk;
            a1 += r2[j] * wk;
        }
        sW1s[h0 * 128 + k]       = a0;
        sW1s[(h0 + 2) * 128 + k] = a1;
    }

    // ---- stage kv via DMA: 16 global_load_lds per thread, all in flight ----
    const float4* src = (const float4*)(kv_x + (size_t)bt * MM * KD);
    #pragma unroll
    for (int k = 0; k < 16; ++k) {
        int idx  = tid + k * 256;
        int gidx = (idx < MM * 32) ? idx : (MM * 32 - 1);  // clamp tail (junk -> row 127)
        __builtin_amdgcn_global_load_lds((gas_t)(src + gidx),
                                         (las_t)(&skv[(k * 256 + wv_ * 64) * 4]),
                                         16, 0, 0);
    }
    asm volatile("s_waitcnt vmcnt(0)" ::: "memory");
    __syncthreads();                   // skv + sW1s ready

    float4 w1s[NH];
    #pragma unroll
    for (int h = 0; h < NH; ++h)
        w1s[h] = *(const float4*)&sW1s[h * KD + dq * 4];

    // ---- scores: row-pair conflict-free b128 reads + head butterfly ----
    const int bit4 = (tid >> 4) & 1;
    const int bit3 = (tid >> 3) & 1;
    const int myh  = bit4 * 2 + bit3;
    #pragma unroll
    for (int k = 0; k < 16; ++k) {
        int m = g + 8 * k;
        float4 v = *(const float4*)&skv[m * KD + dq * 4];
        float p0 = v.x*w1s[0].x + v.y*w1s[0].y + v.z*w1s[0].z + v.w*w1s[0].w;
        float p1 = v.x*w1s[1].x + v.y*w1s[1].y + v.z*w1s[1].z + v.w*w1s[1].w;
        float p2 = v.x*w1s[2].x + v.y*w1s[2].y + v.z*w1s[2].z + v.w*w1s[2].w;
        float p3 = v.x*w1s[3].x + v.y*w1s[3].y + v.z*w1s[3].z + v.w*w1s[3].w;
        float x = bit4 ? p0 : p2;
        float y = bit4 ? p1 : p3;
        float a = (bit4 ? p2 : p0) + __shfl_xor(x, 16);
        float b = (bit4 ? p3 : p1) + __shfl_xor(y, 16);
        float z = bit3 ? a : b;
        float vr = (bit3 ? b : a) + __shfl_xor(z, 8);
        vr += __shfl_xor(vr, 4);
        vr += __shfl_xor(vr, 2);
        vr += __shfl_xor(vr, 1);
        if ((tid & 7) == 0 && m < MM) ssc[m * 4 + myh] = vr;
    }
    __syncthreads();

    // ---- softmax over m: one wave per head ----
    {
        int h = tid >> 6, lane = tid & 63;
        float v0 = ssc[lane * 4 + h];
        bool has1 = (lane + 64) < MM;
        float v1 = has1 ? ssc[(lane + 64) * 4 + h] : -1e30f;
        float mx = fmaxf(v0, v1);
        #pragma unroll
        for (int off = 32; off; off >>= 1) mx = fmaxf(mx, __shfl_xor(mx, off));
        float e0 = __expf(v0 - mx);
        float e1 = has1 ? __expf(v1 - mx) : 0.f;
        float s = e0 + e1;
        #pragma unroll
        for (int off = 32; off; off >>= 1) s += __shfl_xor(s, off);
        float inv = 1.f / s;
        swt[lane * 4 + h] = e0 * inv;
        swt[(lane + 64) * 4 + h] = has1 ? e1 * inv : 0.f;  // m=127 -> 0 (kills junk row)
    }
    __syncthreads();

    // ---- csum, 1x LDS traffic: 128 threads, 4 row-groups x 32 rows,
    //      all 4 heads accumulated in registers ----
    if (tid < 128) {
        const int cg = tid >> 5;       // row-group 0..3
        float4 ca0 = make_float4(0.f,0.f,0.f,0.f);
        float4 ca1 = make_float4(0.f,0.f,0.f,0.f);
        float4 ca2 = make_float4(0.f,0.f,0.f,0.f);
        float4 ca3 = make_float4(0.f,0.f,0.f,0.f);
        #pragma unroll 8
        for (int r = 0; r < 32; ++r) {
            int m = cg * 32 + r;
            float4 w4 = *(const float4*)&swt[m * 4];           // broadcast
            float4 kq = *(const float4*)&skv[m * KD + dq * 4]; // row-pair, conflict-free
            ca0.x += w4.x*kq.x; ca0.y += w4.x*kq.y; ca0.z += w4.x*kq.z; ca0.w += w4.x*kq.w;
            ca1.x += w4.y*kq.x; ca1.y += w4.y*kq.y; ca1.z += w4.y*kq.z; ca1.w += w4.y*kq.w;
            ca2.x += w4.z*kq.x; ca2.y += w4.z*kq.y; ca2.z += w4.z*kq.z; ca2.w += w4.z*kq.w;
            ca3.x += w4.w*kq.x; ca3.y += w4.w*kq.y; ca3.z += w4.w*kq.z; ca3.w += w4.w*kq.w;
        }
        *(float4*)&cpart[cg][0 * KD + dq * 4] = ca0;
        *(float4*)&cpart[cg][1 * KD + dq * 4] = ca1;
        *(float4*)&cpart[cg][2 * KD + dq * 4] = ca2;
        *(float4*)&cpart[cg][3 * KD + dq * 4] = ca3;
    }
    __syncthreads();

    // ---- reduce 4 partials, coalesced float4 write of c ----
    if (tid < 128) {
        float4 a = *(const float4*)&cpart[0][tid * 4];
        float4 b = *(const float4*)&cpart[1][tid * 4];
        float4 c = *(const float4*)&cpart[2][tid * 4];
        float4 d = *(const float4*)&cpart[3][tid * 4];
        float4 s;
        s.x = a.x + b.x + c.x + d.x;
        s.y = a.y + b.y + c.y + d.y;
        s.z = a.z + b.z + c.z + d.z;
        s.w = a.w + b.w + c.w + d.w;
        *(float4*)(ws + OFF_C + (size_t)bt * 512 + tid * 4) = s;
    }
}

// ---------------------------------------------------------------------------
// Kernel 2: out[r][h*128+dd] = sum_c A_h[r][c]*Wct[h][c][dd] + bv,  K=256,
// A_h[r] = [ c[r][h][0:128] | q_x[r][0:128] ].
// BM=32 x BN=64, BK=64, 256 WGs, 2x4 register blocking, b64/b128 LDS reads.
// ---------------------------------------------------------------------------
#define BM 32
#define BN 64
#define BK 64
#define AP 34   // sAT row pad (even -> b64-aligned, 2-way max)
#define BP 68   // sB row pad (16B-aligned float4 reads, conflict-free)

__global__ __launch_bounds__(256, 2)
void proj_out(const float* __restrict__ q_x,
              const float* __restrict__ bv,
              const float* __restrict__ ws,
              float* __restrict__ out) {
    __shared__ float sAT[BK][AP];   // A transposed [c][r]
    __shared__ float sB[BK][BP];    // B [c][dd]

    const int r0  = blockIdx.x * BM;
    const int dd0 = blockIdx.y * BN;
    const int h   = blockIdx.z;
    const int tid = threadIdx.x;
    const int tx  = tid & 15;       // 16 col-groups x 4 cols
    const int ty  = tid >> 4;       // 16 row-groups x 2 rows
    const float* cmat = ws + OFF_C;
    const float* Wct  = ws + OFF_WC;

    float acc[2][4];
    #pragma unroll
    for (int i = 0; i < 2; ++i)
        #pragma unroll
        for (int j = 0; j < 4; ++j) acc[i][j] = 0.f;

    for (int ks = 0; ks < 4; ++ks) {
        int kk0 = ks * BK;
        const float* Abase; int Astride;
        if (kk0 < 128) { Abase = cmat + h * KD + kk0; Astride = 512; }
        else           { Abase = q_x + (kk0 - 128);   Astride = KD;  }
        #pragma unroll
        for (int i = 0; i < 2; ++i) {
            int idx = tid + i * 256;         // 0..511
            int r = idx >> 4, c4 = idx & 15;
            float4 v = *(const float4*)(Abase + (size_t)(r0 + r) * Astride + c4 * 4);
            sAT[c4 * 4 + 0][r] = v.x;
            sAT[c4 * 4 + 1][r] = v.y;
            sAT[c4 * 4 + 2][r] = v.z;
            sAT[c4 * 4 + 3][r] = v.w;
        }
        #pragma unroll
        for (int i = 0; i < 4; ++i) {
            int idx = tid + i * 256;         // 0..1023
            int c = idx >> 4, d4 = idx & 15;
            *(float4*)&sB[c][d4 * 4] =
                *(const float4*)(Wct + (size_t)(h * 256 + kk0 + c) * 128 + dd0 + d4 * 4);
        }
        __syncthreads();
        #pragma unroll 8
        for (int c = 0; c < BK; ++c) {
            float2 a  = *(const float2*)&sAT[c][ty * 2];
            float4 b4 = *(const float4*)&sB[c][tx * 4];
            acc[0][0] += a.x * b4.x; acc[0][1] += a.x * b4.y;
            acc[0][2] += a.x * b4.z; acc[0][3] += a.x * b4.w;
            acc[1][0] += a.y * b4.x; acc[1][1] += a.y * b4.y;
            acc[1][2] += a.y * b4.z; acc[1][3] += a.y * b4.w;
        }
        __syncthreads();
    }
    float bb[4];
    #pragma unroll
    for (int j = 0; j < 4; ++j) bb[j] = bv[h * 129 + 1 + dd0 + tx * 4 + j];
    #pragma unroll
    for (int i = 0; i < 2; ++i) {
        float4 v;
        v.x = acc[i][0] + bb[0];
        v.y = acc[i][1] + bb[1];
        v.z = acc[i][2] + bb[2];
        v.w = acc[i][3] + bb[3];
        *(float4*)(out + (size_t)(r0 + ty * 2 + i) * 512 + h * KD + dd0 + tx * 4) = v;
    }
}

extern "C" void kernel_launch(void* const* d_in, const int* in_sizes, int n_in,
                              void* d_out, int out_size, void* d_ws, size_t ws_size,
                              hipStream_t stream) {
    const float* q_x  = (const float*)d_in[0];
    const float* kv_x = (const float*)d_in[1];
    const float* Wk   = (const float*)d_in[2];
    const float* Wq   = (const float*)d_in[3];
    const float* Wv   = (const float*)d_in[4];
    const float* bv   = (const float*)d_in[5];
    float* out = (float*)d_out;
    float* ws  = (float*)d_ws;

    int bt = in_sizes[0] / KD;   // 1024

    hipLaunchKernelGGL(attn_fused, dim3(NPRE + bt), dim3(256), 0, stream,
                       kv_x, Wk, Wq, Wv, ws);
    hipLaunchKernelGGL(proj_out, dim3(bt / BM, KD / BN, NH), dim3(256), 0, stream,
                       q_x, bv, ws, out);
}

// Round 7
// 42.299 us; speedup vs baseline: 1.2385x; 1.2385x over previous
//
#include <hip/hip_runtime.h>

// Shapes fixed by setup_inputs(): b=8, t=128, k=128, h=4, m=t-1=127.
#define KD 128
#define NH 4
#define MM 127
#define NO 516

// workspace layout (float offsets)
#define OFF_W1S 0                      // [4][128]   score rows of W1
#define OFF_WC  512                    // [4][256][128]  Wct[h][c][dd]  (c-major)
#define OFF_C   (512 + 131072)         // [1024][512]  weighted kv sums per (bt, h*128+d)

// ---------------------------------------------------------------------------
// Kernel 1: W1[o][k] = sum_j Wv[o][j]*Wk[j][k],  W2[o][k] = sum_j Wv[o][128+j]*Wq[j][k]
// Score rows (o%129==0) -> OFF_W1S. Value rows -> Wct[h][c][dd] (c-major).
// (q/W2/bias score terms are constant in m -> cancel in softmax -> dropped.)
// ---------------------------------------------------------------------------
__global__ void precompute_w(const float* __restrict__ Wk,
                             const float* __restrict__ Wq,
                             const float* __restrict__ Wv,
                             float* __restrict__ ws) {
    int o = blockIdx.x;        // 0..515
    int k = threadIdx.x;       // 0..127
    const float* wvrow = Wv + o * 256;
    float acc1 = 0.f, acc2 = 0.f;
    #pragma unroll 8
    for (int j = 0; j < 128; ++j) {
        acc1 += wvrow[j]       * Wk[j * 128 + k];
        acc2 += wvrow[128 + j] * Wq[j * 128 + k];
    }
    int h = o / 129;
    int r = o - h * 129;
    if (r == 0) {
        ws[OFF_W1S + h * 128 + k] = acc1;
    } else {
        int dd = r - 1;
        ws[OFF_WC + (size_t)(h * 256 + k) * 128 + dd]       = acc1;
        ws[OFF_WC + (size_t)(h * 256 + 128 + k) * 128 + dd] = acc2;
    }
}

// ---------------------------------------------------------------------------
// Kernel 2: per (b,t): scores (stream kv from global) -> softmax ->
// csum (re-stream kv from L2/L3). NO kv staging: LDS is only 20.5 KB ->
// 4 WG/CU, 16 waves/CU (rounds 2-6 were stuck at 2 WG/CU with a
// vmcnt(0)-drained 65-80 KB LDS tile -> latency-bound at ~800 GB/s).
// ---------------------------------------------------------------------------
__global__ __launch_bounds__(256, 4)
void attn_bt(const float* __restrict__ kv_x, float* __restrict__ ws) {
    __shared__ float ssc[512];         // scores [m][h]   (2 KB)
    __shared__ float swt[512];         // weights [m][h]  (2 KB)
    __shared__ float cpart[8][512];    // group partials  (16 KB)

    const int bt  = blockIdx.x;
    const int tid = threadIdx.x;
    const int dq  = tid & 31;          // d-quad (d = dq*4+j)
    const int g   = tid >> 5;          // 32-lane group 0..7 (owns rows m = g+8k)

    // score-projection fragments for my d-quad, all 4 heads (2 KB, L2-hot)
    float4 w1s[NH];
    #pragma unroll
    for (int h = 0; h < NH; ++h)
        w1s[h] = *(const float4*)(ws + OFF_W1S + h * KD + dq * 4);

    const float4* src = (const float4*)(kv_x + (size_t)bt * MM * KD);
    const int bit4 = (tid >> 4) & 1;
    const int bit3 = (tid >> 3) & 1;
    const int myh  = bit4 * 2 + bit3;

    // ---- phase A: scores, 2-deep register-prefetched global stream ----
    // wave = rows m and m+1 -> 1 KB contiguous per wave-load, coalesced.
    float4 cur = src[g * 32 + dq];                 // k=0 (m=g     < 127)
    float4 nxt = src[(g + 8) * 32 + dq];           // k=1 (m=g+8   < 127)
    #pragma unroll
    for (int k = 0; k < 16; ++k) {
        int mp = g + 8 * (k + 2);
        float4 pre = make_float4(0.f, 0.f, 0.f, 0.f);
        if (k < 14 && mp < MM) pre = src[mp * 32 + dq];
        int m = g + 8 * k;
        float4 v = cur;
        float p0 = v.x*w1s[0].x + v.y*w1s[0].y + v.z*w1s[0].z + v.w*w1s[0].w;
        float p1 = v.x*w1s[1].x + v.y*w1s[1].y + v.z*w1s[1].z + v.w*w1s[1].w;
        float p2 = v.x*w1s[2].x + v.y*w1s[2].y + v.z*w1s[2].z + v.w*w1s[2].w;
        float p3 = v.x*w1s[3].x + v.y*w1s[3].y + v.z*w1s[3].z + v.w*w1s[3].w;
        // head-splitting butterfly over the 32-lane group
        float x = bit4 ? p0 : p2;
        float y = bit4 ? p1 : p3;
        float a = (bit4 ? p2 : p0) + __shfl_xor(x, 16);
        float b = (bit4 ? p3 : p1) + __shfl_xor(y, 16);
        float z = bit3 ? a : b;
        float vr = (bit3 ? b : a) + __shfl_xor(z, 8);
        vr += __shfl_xor(vr, 4);
        vr += __shfl_xor(vr, 2);
        vr += __shfl_xor(vr, 1);
        if ((tid & 7) == 0 && m < MM) ssc[m * 4 + myh] = vr;
        cur = nxt; nxt = pre;
    }
    __syncthreads();

    // ---- softmax over m: one wave per head ----
    {
        int h = tid >> 6, lane = tid & 63;
        float v0 = ssc[lane * 4 + h];
        bool has1 = (lane + 64) < MM;
        float v1 = has1 ? ssc[(lane + 64) * 4 + h] : -1e30f;
        float mx = fmaxf(v0, v1);
        #pragma unroll
        for (int off = 32; off; off >>= 1) mx = fmaxf(mx, __shfl_xor(mx, off));
        float e0 = __expf(v0 - mx);
        float e1 = has1 ? __expf(v1 - mx) : 0.f;
        float s = e0 + e1;
        #pragma unroll
        for (int off = 32; off; off >>= 1) s += __shfl_xor(s, off);
        float inv = 1.f / s;
        swt[lane * 4 + h] = e0 * inv;
        swt[(lane + 64) * 4 + h] = has1 ? e1 * inv : 0.f;
    }
    __syncthreads();

    // ---- phase C: csum, re-stream kv (L2/L3-hot from phase A) ----
    float4 c0 = make_float4(0.f,0.f,0.f,0.f);
    float4 c1 = make_float4(0.f,0.f,0.f,0.f);
    float4 c2 = make_float4(0.f,0.f,0.f,0.f);
    float4 c3 = make_float4(0.f,0.f,0.f,0.f);
    #pragma unroll
    for (int k = 0; k < 16; ++k) {
        int m = g + 8 * k;
        if (m < MM) {                                   // uniform per group
            float4 kq = src[m * 32 + dq];               // coalesced
            float4 w4 = *(const float4*)&swt[m * 4];    // LDS broadcast
            c0.x += w4.x*kq.x; c0.y += w4.x*kq.y; c0.z += w4.x*kq.z; c0.w += w4.x*kq.w;
            c1.x += w4.y*kq.x; c1.y += w4.y*kq.y; c1.z += w4.y*kq.z; c1.w += w4.y*kq.w;
            c2.x += w4.z*kq.x; c2.y += w4.z*kq.y; c2.z += w4.z*kq.z; c2.w += w4.z*kq.w;
            c3.x += w4.w*kq.x; c3.y += w4.w*kq.y; c3.z += w4.w*kq.z; c3.w += w4.w*kq.w;
        }
    }
    *(float4*)&cpart[g][0 * KD + dq * 4] = c0;
    *(float4*)&cpart[g][1 * KD + dq * 4] = c1;
    *(float4*)&cpart[g][2 * KD + dq * 4] = c2;
    *(float4*)&cpart[g][3 * KD + dq * 4] = c3;
    __syncthreads();

    // ---- reduce 8 group-partials, coalesced write of c ----
    float* cdst = ws + OFF_C + (size_t)bt * 512;
    #pragma unroll
    for (int rep = 0; rep < 2; ++rep) {
        int o = tid + rep * 256;
        float s = 0.f;
        #pragma unroll
        for (int gg = 0; gg < 8; ++gg) s += cpart[gg][o];
        cdst[o] = s;
    }
}

// ---------------------------------------------------------------------------
// Kernel 3: out[r][h*128+dd] = sum_c A_h[r][c]*Wct[h][c][dd] + bv,  K=256,
// A_h[r] = [ c[r][h][0:128] | q_x[r][0:128] ].
// BM=32 x BN=64, BK=64, 256 WGs, 2x4 register blocking, b64/b128 LDS reads.
// ---------------------------------------------------------------------------
#define BM 32
#define BN 64
#define BK 64
#define AP 34   // sAT row pad (even -> b64-aligned, 2-way max)
#define BP 68   // sB row pad (16B-aligned float4 reads, conflict-free)

__global__ __launch_bounds__(256, 2)
void proj_out(const float* __restrict__ q_x,
              const float* __restrict__ bv,
              const float* __restrict__ ws,
              float* __restrict__ out) {
    __shared__ float sAT[BK][AP];   // A transposed [c][r]
    __shared__ float sB[BK][BP];    // B [c][dd]

    const int r0  = blockIdx.x * BM;
    const int dd0 = blockIdx.y * BN;
    const int h   = blockIdx.z;
    const int tid = threadIdx.x;
    const int tx  = tid & 15;       // 16 col-groups x 4 cols
    const int ty  = tid >> 4;       // 16 row-groups x 2 rows
    const float* cmat = ws + OFF_C;
    const float* Wct  = ws + OFF_WC;

    float acc[2][4];
    #pragma unroll
    for (int i = 0; i < 2; ++i)
        #pragma unroll
        for (int j = 0; j < 4; ++j) acc[i][j] = 0.f;

    for (int ks = 0; ks < 4; ++ks) {
        int kk0 = ks * BK;
        const float* Abase; int Astride;
        if (kk0 < 128) { Abase = cmat + h * KD + kk0; Astride = 512; }
        else           { Abase = q_x + (kk0 - 128);   Astride = KD;  }
        #pragma unroll
        for (int i = 0; i < 2; ++i) {
            int idx = tid + i * 256;         // 0..511
            int r = idx >> 4, c4 = idx & 15;
            float4 v = *(const float4*)(Abase + (size_t)(r0 + r) * Astride + c4 * 4);
            sAT[c4 * 4 + 0][r] = v.x;
            sAT[c4 * 4 + 1][r] = v.y;
            sAT[c4 * 4 + 2][r] = v.z;
            sAT[c4 * 4 + 3][r] = v.w;
        }
        #pragma unroll
        for (int i = 0; i < 4; ++i) {
            int idx = tid + i * 256;         // 0..1023
            int c = idx >> 4, d4 = idx & 15;
            *(float4*)&sB[c][d4 * 4] =
                *(const float4*)(Wct + (size_t)(h * 256 + kk0 + c) * 128 + dd0 + d4 * 4);
        }
        __syncthreads();
        #pragma unroll 8
        for (int c = 0; c < BK; ++c) {
            float2 a  = *(const float2*)&sAT[c][ty * 2];
            float4 b4 = *(const float4*)&sB[c][tx * 4];
            acc[0][0] += a.x * b4.x; acc[0][1] += a.x * b4.y;
            acc[0][2] += a.x * b4.z; acc[0][3] += a.x * b4.w;
            acc[1][0] += a.y * b4.x; acc[1][1] += a.y * b4.y;
            acc[1][2] += a.y * b4.z; acc[1][3] += a.y * b4.w;
        }
        __syncthreads();
    }
    float bb[4];
    #pragma unroll
    for (int j = 0; j < 4; ++j) bb[j] = bv[h * 129 + 1 + dd0 + tx * 4 + j];
    #pragma unroll
    for (int i = 0; i < 2; ++i) {
        float4 v;
        v.x = acc[i][0] + bb[0];
        v.y = acc[i][1] + bb[1];
        v.z = acc[i][2] + bb[2];
        v.w = acc[i][3] + bb[3];
        *(float4*)(out + (size_t)(r0 + ty * 2 + i) * 512 + h * KD + dd0 + tx * 4) = v;
    }
}

extern "C" void kernel_launch(void* const* d_in, const int* in_sizes, int n_in,
                              void* d_out, int out_size, void* d_ws, size_t ws_size,
                              hipStream_t stream) {
    const float* q_x  = (const float*)d_in[0];
    const float* kv_x = (const float*)d_in[1];
    const float* Wk   = (const float*)d_in[2];
    const float* Wq   = (const float*)d_in[3];
    const float* Wv   = (const float*)d_in[4];
    const float* bv   = (const float*)d_in[5];
    float* out = (float*)d_out;
    float* ws  = (float*)d_ws;

    int bt = in_sizes[0] / KD;   // 1024

    hipLaunchKernelGGL(precompute_w, dim3(NO), dim3(128), 0, stream, Wk, Wq, Wv, ws);
    hipLaunchKernelGGL(attn_bt, dim3(bt), dim3(256), 0, stream, kv_x, ws);
    hipLaunchKernelGGL(proj_out, dim3(bt / BM, KD / BN, NH), dim3(256), 0, stream,
                       q_x, bv, ws, out);
}